// Round 3
// baseline (513.028 us; speedup 1.0000x reference)
//
#include <hip/hip_runtime.h>
#include <stdint.h>

#define T_TOK 4096
#define Hd    1024
#define Id    512
#define NE    16
#define NSLOT 32
#define TOPK  4
#define CAPR  (T_TOK*TOPK)
#define MAXTILES 144

typedef __bf16 bf16x8 __attribute__((ext_vector_type(8)));
typedef float  floatx4 __attribute__((ext_vector_type(4)));

#define WAIT_VM(n) asm volatile("s_waitcnt vmcnt(" #n ")" ::: "memory")

static __device__ __forceinline__ void wg_barrier(){
  asm volatile("" ::: "memory");
  __builtin_amdgcn_s_barrier();
  asm volatile("" ::: "memory");
}

static __device__ __forceinline__ unsigned short f2bf(float f){
  unsigned int u = __float_as_uint(f);
  u = u + 0x7fffu + ((u >> 16) & 1u);
  return (unsigned short)(u >> 16);
}

static __device__ __forceinline__ void load_lds16(const void* g, void* l){
  __builtin_amdgcn_global_load_lds((const __attribute__((address_space(1))) void*)g,
                                   (__attribute__((address_space(3))) void*)l, 16, 0, 0);
}

// ---------------- fused prep: x->bf16 + 3 weight transposes ----------------
// blocks [0,6144): transpose-convert (2048 per array); [6144,7168): x cvt
__global__ __launch_bounds__(256) void prep_kernel(
    const float* __restrict__ wg, const float* __restrict__ wu,
    const float* __restrict__ wd, const float* __restrict__ x,
    unsigned short* __restrict__ wgb, unsigned short* __restrict__ wub,
    unsigned short* __restrict__ wdb, unsigned short* __restrict__ xb){
  __shared__ float tile[64][65];
  const int bid = blockIdx.x;
  const int tid = threadIdx.x;
  if (bid < 6144){
    const float* src; unsigned short* dst; int R, C, cx, ry;
    const int arr = bid >> 11;
    const int rem = bid & 2047;
    const int e = rem >> 7;
    const int r2 = rem & 127;
    if (arr == 0){ src = wg; dst = wgb; R = Hd; C = Id; cx = r2 & 7;  ry = r2 >> 3; }
    else if (arr == 1){ src = wu; dst = wub; R = Hd; C = Id; cx = r2 & 7;  ry = r2 >> 3; }
    else { src = wd; dst = wdb; R = Id; C = Hd; cx = r2 & 15; ry = r2 >> 4; }
    const int c0 = cx * 64, r0 = ry * 64;
    const float* s = src + (size_t)e * R * C;
    unsigned short* d = dst + (size_t)e * R * C;
    const int lr = tid >> 4;
    const int lc = (tid & 15) * 4;
    #pragma unroll
    for (int p = 0; p < 4; ++p){
      int r = p*16 + lr;
      float4 v = *(const float4*)(s + (size_t)(r0 + r)*C + c0 + lc);
      tile[r][lc+0] = v.x; tile[r][lc+1] = v.y; tile[r][lc+2] = v.z; tile[r][lc+3] = v.w;
    }
    __syncthreads();
    #pragma unroll
    for (int p = 0; p < 4; ++p){
      int c = p*16 + lr;
      ushort4 o;
      o.x = f2bf(tile[lc+0][c]); o.y = f2bf(tile[lc+1][c]);
      o.z = f2bf(tile[lc+2][c]); o.w = f2bf(tile[lc+3][c]);
      *(ushort4*)(d + (size_t)(c0 + c)*R + r0 + lc) = o;
    }
  } else {
    const int ib = (bid - 6144) * 1024;
    #pragma unroll
    for (int p = 0; p < 4; ++p){
      int i = ib + p*256 + tid;
      float4 v = ((const float4*)x)[i];
      ushort4 o;
      o.x = f2bf(v.x); o.y = f2bf(v.y); o.z = f2bf(v.z); o.w = f2bf(v.w);
      ((ushort4*)xb)[i] = o;
    }
  }
}

// ---------------- fp32 router logits (atomic-free, full K per block) ----------------
__global__ __launch_bounds__(256) void logits_kernel(const float* __restrict__ x,
    const float* __restrict__ rw, float* __restrict__ logits, int* __restrict__ counts){
  if (blockIdx.x == 0 && threadIdx.x < NE) counts[threadIdx.x] = 0;
  __shared__ float srw[NSLOT][260];
  const int tid = threadIdx.x;
  const int t  = blockIdx.x * 32 + (tid >> 3);
  const int s0 = (tid & 7) * 4;
  float4 acc = {0.f, 0.f, 0.f, 0.f};
  for (int c = 0; c < 4; ++c){
    const int kc = c * 256;
    __syncthreads();
    #pragma unroll
    for (int p = 0; p < 8; ++p){
      int idx = tid + p*256;
      int s = idx >> 6;
      int col = (idx & 63) << 2;
      *(float4*)&srw[s][col] = *(const float4*)(rw + (size_t)s*Hd + kc + col);
    }
    __syncthreads();
    for (int k = 0; k < 256; k += 4){
      float4 xv = *(const float4*)(x + (size_t)t*Hd + kc + k);
      float4 r0 = *(const float4*)&srw[s0+0][k];
      float4 r1 = *(const float4*)&srw[s0+1][k];
      float4 r2 = *(const float4*)&srw[s0+2][k];
      float4 r3 = *(const float4*)&srw[s0+3][k];
      acc.x += xv.x*r0.x + xv.y*r0.y + xv.z*r0.z + xv.w*r0.w;
      acc.y += xv.x*r1.x + xv.y*r1.y + xv.z*r1.z + xv.w*r1.w;
      acc.z += xv.x*r2.x + xv.y*r2.y + xv.z*r2.z + xv.w*r2.w;
      acc.w += xv.x*r3.x + xv.y*r3.y + xv.z*r3.z + xv.w*r3.w;
    }
  }
  *(float4*)(logits + (size_t)t*NSLOT + s0) = acc;
}

// ---------------- softmax + bias + top-4 + (out = zw*x) fused ----------------
__global__ __launch_bounds__(256) void topk_kernel(
    const float* __restrict__ logits, const float* __restrict__ bias,
    const float* __restrict__ x,
    int* __restrict__ counts, int* __restrict__ tkid, float* __restrict__ tkw,
    float* __restrict__ out){
  __shared__ float szw[256];
  const int tid = threadIdx.x;
  const int t = blockIdx.x * 256 + tid;
  float sc[32], bsc[32];
  #pragma unroll
  for (int i = 0; i < 32; i += 4){
    float4 v = *(const float4*)(logits + (size_t)t*NSLOT + i);
    sc[i] = v.x; sc[i+1] = v.y; sc[i+2] = v.z; sc[i+3] = v.w;
  }
  float mx = sc[0];
  #pragma unroll
  for (int i = 1; i < 32; ++i) mx = fmaxf(mx, sc[i]);
  float sum = 0.f;
  #pragma unroll
  for (int i = 0; i < 32; ++i){ sc[i] = __expf(sc[i]-mx); sum += sc[i]; }
  float inv = 1.f / sum;
  #pragma unroll
  for (int i = 0; i < 32; ++i){ sc[i] *= inv; bsc[i] = sc[i] + bias[i]; }
  unsigned int chosen = 0;
  float zw = 0.f;
  #pragma unroll
  for (int k = 0; k < TOPK; ++k){
    float bv = -1e30f, bw = 0.f; int best = 0;
    #pragma unroll
    for (int i = 0; i < 32; ++i){
      float v = ((chosen >> i) & 1u) ? -1e30f : bsc[i];
      if (v > bv){ bv = v; best = i; bw = sc[i]; }
    }
    chosen |= (1u << best);
    tkid[t*TOPK + k] = best;
    tkw[t*TOPK + k]  = bw;
    if (best < NE) atomicAdd(&counts[best], 1);
    else zw += bw;
  }
  szw[tid] = zw;
  __syncthreads();
  // phase 2: out rows for this block's 256 tokens
  const int lane = tid & 63, wid = tid >> 6;
  const size_t base = (size_t)blockIdx.x * 256 * Hd;
  for (int r = wid; r < 256; r += 4){
    float s = szw[r];
    const float4* xs = (const float4*)(x + base + (size_t)r*Hd);
    float4* os = (float4*)(out + base + (size_t)r*Hd);
    #pragma unroll
    for (int q = 0; q < 4; ++q){
      float4 v = xs[lane + q*64];
      float4 o; o.x = v.x*s; o.y = v.y*s; o.z = v.z*s; o.w = v.w*s;
      os[lane + q*64] = o;
    }
  }
}

// ---------------- offsets scan + tile list (tiny) ----------------
__global__ void offsets_kernel(const int* __restrict__ counts,
                               int* __restrict__ offsets, int* __restrict__ cursors,
                               int* __restrict__ tilelist, int* __restrict__ ntiles){
  if (threadIdx.x == 0){
    int acc = 0;
    for (int e = 0; e < NE; ++e){ offsets[e] = acc; acc += counts[e]; }
    offsets[NE] = acc;
    int n = 0;
    for (int e = 0; e < NE; ++e){
      int ne = counts[e];
      for (int m = 0; m*128 < ne; ++m) tilelist[n++] = (e << 16) | m;
    }
    ntiles[0] = n;
  }
  if (threadIdx.x < NE) cursors[threadIdx.x] = 0;
}

// ---------------- build compact per-expert row lists ----------------
__global__ __launch_bounds__(256) void build_kernel(
    const int* __restrict__ tkid, const float* __restrict__ tkw,
    const int* __restrict__ offsets, int* __restrict__ cursors,
    int* __restrict__ rowmap, float* __restrict__ roww){
  int i = blockIdx.x * 256 + threadIdx.x;
  int id = tkid[i];
  if (id < NE){
    int pos = atomicAdd(&cursors[id], 1);
    int row = offsets[id] + pos;
    rowmap[row] = i >> 2;
    roww[row]   = tkw[i];
  }
}

// ---------------- fused gate+up GEMM + SwiGLU (128x128, dbuf, tile-list) ----------------
__global__ __launch_bounds__(256, 3) void gateup_kernel(
    const unsigned short* __restrict__ xb,
    const unsigned short* __restrict__ wgb,
    const unsigned short* __restrict__ wub,
    const int* __restrict__ offsets,
    const int* __restrict__ rowmap,
    const float* __restrict__ roww,
    const int* __restrict__ tilelist,
    const int* __restrict__ ntiles,
    unsigned short* __restrict__ act){
  const int b = blockIdx.x;
  const int tile = b >> 2;
  if (tile >= ntiles[0]) return;
  const int packed = tilelist[tile];
  const int e  = packed >> 16;
  const int m0 = (packed & 0xffff) * 128;
  const int n0 = (b & 3) * 128;
  const int off = offsets[e];
  const int ne  = offsets[e+1] - off;

  __shared__ unsigned short sA [2][128*32];
  __shared__ unsigned short sBg[2][128*32];
  __shared__ unsigned short sBu[2][128*32];
  __shared__ int sT[128];

  const int tid  = threadIdx.x;
  const int lane = tid & 63;
  const int wid  = tid >> 6;

  if (tid < 128){
    int r = m0 + tid;
    sT[tid] = rowmap[off + ((r < ne) ? r : 0)];
  }
  __syncthreads();

  const int r_in = lane >> 2;
  const int seg  = lane & 3;
  const int rt0  = wid*32 + r_in;
  const int rt1  = rt0 + 16;
  const size_t wbase = (size_t)e * Id * Hd;

  const unsigned short* pA0 = xb + (size_t)sT[rt0]*Hd + seg*8;
  const unsigned short* pA1 = xb + (size_t)sT[rt1]*Hd + seg*8;
  const unsigned short* pG0 = wgb + wbase + (size_t)(n0+rt0)*Hd + seg*8;
  const unsigned short* pG1 = wgb + wbase + (size_t)(n0+rt1)*Hd + seg*8;
  const unsigned short* pU0 = wub + wbase + (size_t)(n0+rt0)*Hd + seg*8;
  const unsigned short* pU1 = wub + wbase + (size_t)(n0+rt1)*Hd + seg*8;
  const int dA0 = wid*1024;
  const int dA1 = wid*1024 + 512;

  floatx4 accg[4][4], accu[4][4];
  #pragma unroll
  for (int i = 0; i < 4; ++i)
    #pragma unroll
    for (int j = 0; j < 4; ++j){
      floatx4 z = {0.f,0.f,0.f,0.f};
      accg[i][j] = z; accu[i][j] = z;
    }

  const int wm = (wid & 1) * 64;
  const int wn = (wid >> 1) * 64;
  const int fm = lane & 15;
  const int fq = lane >> 4;

  load_lds16(pA0, &sA[0][dA0]);  load_lds16(pA1, &sA[0][dA1]);
  load_lds16(pG0, &sBg[0][dA0]); load_lds16(pG1, &sBg[0][dA1]);
  load_lds16(pU0, &sBu[0][dA0]); load_lds16(pU1, &sBu[0][dA1]);

  #pragma unroll 2
  for (int kit = 0; kit < 32; ++kit){
    const int cur = kit & 1;
    if (kit < 31){
      const int nk = (kit+1)*32;
      const int nb = 1 - cur;
      load_lds16(pA0 + nk, &sA[nb][dA0]);  load_lds16(pA1 + nk, &sA[nb][dA1]);
      load_lds16(pG0 + nk, &sBg[nb][dA0]); load_lds16(pG1 + nk, &sBg[nb][dA1]);
      load_lds16(pU0 + nk, &sBu[nb][dA0]); load_lds16(pU1 + nk, &sBu[nb][dA1]);
      WAIT_VM(6);
    } else {
      WAIT_VM(0);
    }
    wg_barrier();
    bf16x8 av[4], bgv[4], buv[4];
    #pragma unroll
    for (int i = 0; i < 4; ++i)
      av[i] = *(const bf16x8*)(&sA[cur][(wm + i*16 + fm)*32 + fq*8]);
    #pragma unroll
    for (int j = 0; j < 4; ++j){
      bgv[j] = *(const bf16x8*)(&sBg[cur][(wn + j*16 + fm)*32 + fq*8]);
      buv[j] = *(const bf16x8*)(&sBu[cur][(wn + j*16 + fm)*32 + fq*8]);
    }
    #pragma unroll
    for (int i = 0; i < 4; ++i)
      #pragma unroll
      for (int j = 0; j < 4; ++j){
        accg[i][j] = __builtin_amdgcn_mfma_f32_16x16x32_bf16(av[i], bgv[j], accg[i][j], 0, 0, 0);
        accu[i][j] = __builtin_amdgcn_mfma_f32_16x16x32_bf16(av[i], buv[j], accu[i][j], 0, 0, 0);
      }
    wg_barrier();
  }

  #pragma unroll
  for (int i = 0; i < 4; ++i){
    #pragma unroll
    for (int r = 0; r < 4; ++r){
      int row = wm + i*16 + fq*4 + r;
      if (m0 + row < ne){
        float w = roww[off + m0 + row];
        size_t rb = (size_t)(off + m0 + row) * Id + n0;
        #pragma unroll
        for (int j = 0; j < 4; ++j){
          float g = accg[i][j][r];
          float u = accu[i][j][r];
          float a = (g / (1.f + __expf(-g))) * u * w;
          act[rb + wn + j*16 + fm] = f2bf(a);
        }
      }
    }
  }
}

// ---------------- down GEMM + atomic scatter (dbuf, tile-list) ----------------
__global__ __launch_bounds__(256, 4) void down_kernel(
    const unsigned short* __restrict__ act,
    const unsigned short* __restrict__ wdb,
    const int* __restrict__ offsets,
    const int* __restrict__ rowmap,
    const int* __restrict__ tilelist,
    const int* __restrict__ ntiles,
    float* __restrict__ out){
  const int b = blockIdx.x;
  const int tile = b >> 3;
  if (tile >= ntiles[0]) return;
  const int packed = tilelist[tile];
  const int e  = packed >> 16;
  const int m0 = (packed & 0xffff) * 128;
  const int n0 = (b & 7) * 128;
  const int off = offsets[e];
  const int ne  = offsets[e+1] - off;

  __shared__ unsigned short sA[2][128*32];
  __shared__ unsigned short sB[2][128*32];
  __shared__ int sT[128];

  const int tid  = threadIdx.x;
  const int lane = tid & 63;
  const int wid  = tid >> 6;
  if (tid < 128){
    int r = m0 + tid;
    sT[tid] = (r < ne) ? rowmap[off + r] : 0;
  }

  const int r_in = lane >> 2, seg = lane & 3;
  const int rt0 = wid*32 + r_in;
  const int rt1 = rt0 + 16;
  const int gr0 = off + ((m0 + rt0 < ne) ? (m0 + rt0) : 0);
  const int gr1 = off + ((m0 + rt1 < ne) ? (m0 + rt1) : 0);
  const size_t wbase = (size_t)e * Hd * Id;
  const unsigned short* pA0 = act + (size_t)gr0*Id + seg*8;
  const unsigned short* pA1 = act + (size_t)gr1*Id + seg*8;
  const unsigned short* pB0 = wdb + wbase + (size_t)(n0+rt0)*Id + seg*8;
  const unsigned short* pB1 = wdb + wbase + (size_t)(n0+rt1)*Id + seg*8;
  const int dA0 = wid*1024, dA1 = wid*1024 + 512;

  floatx4 acc[4][4];
  #pragma unroll
  for (int i = 0; i < 4; ++i)
    #pragma unroll
    for (int j = 0; j < 4; ++j){ floatx4 z = {0.f,0.f,0.f,0.f}; acc[i][j] = z; }

  const int wm = (wid & 1) * 64, wn = (wid >> 1) * 64;
  const int fm = lane & 15, fq = lane >> 4;

  load_lds16(pA0, &sA[0][dA0]); load_lds16(pA1, &sA[0][dA1]);
  load_lds16(pB0, &sB[0][dA0]); load_lds16(pB1, &sB[0][dA1]);

  #pragma unroll 2
  for (int kit = 0; kit < 16; ++kit){
    const int cur = kit & 1;
    if (kit < 15){
      const int nk = (kit+1)*32;
      const int nb = 1 - cur;
      load_lds16(pA0 + nk, &sA[nb][dA0]); load_lds16(pA1 + nk, &sA[nb][dA1]);
      load_lds16(pB0 + nk, &sB[nb][dA0]); load_lds16(pB1 + nk, &sB[nb][dA1]);
      WAIT_VM(4);
    } else {
      WAIT_VM(0);
    }
    wg_barrier();
    bf16x8 av[4], bv[4];
    #pragma unroll
    for (int i = 0; i < 4; ++i) av[i] = *(const bf16x8*)(&sA[cur][(wm + i*16 + fm)*32 + fq*8]);
    #pragma unroll
    for (int j = 0; j < 4; ++j) bv[j] = *(const bf16x8*)(&sB[cur][(wn + j*16 + fm)*32 + fq*8]);
    #pragma unroll
    for (int i = 0; i < 4; ++i)
      #pragma unroll
      for (int j = 0; j < 4; ++j)
        acc[i][j] = __builtin_amdgcn_mfma_f32_16x16x32_bf16(av[i], bv[j], acc[i][j], 0, 0, 0);
    wg_barrier();
  }

  #pragma unroll
  for (int i = 0; i < 4; ++i){
    #pragma unroll
    for (int r = 0; r < 4; ++r){
      int row = wm + i*16 + fq*4 + r;
      if (m0 + row < ne){
        int t = sT[row];
        #pragma unroll
        for (int j = 0; j < 4; ++j)
          atomicAdd(&out[(size_t)t*Hd + n0 + wn + j*16 + fm], acc[i][j][r]);
      }
    }
  }
}

// =================================================================
extern "C" void kernel_launch(void* const* d_in, const int* in_sizes, int n_in,
                              void* d_out, int out_size, void* d_ws, size_t ws_size,
                              hipStream_t stream){
  (void)in_sizes; (void)n_in; (void)out_size; (void)ws_size;
  const float* x    = (const float*)d_in[0];
  const float* rw   = (const float*)d_in[1];
  const float* bias = (const float*)d_in[2];
  const float* wg   = (const float*)d_in[3];
  const float* wu   = (const float*)d_in[4];
  const float* wd   = (const float*)d_in[5];
  float* out = (float*)d_out;

  char* ws = (char*)d_ws;
  const size_t WSZ = (size_t)NE * Id * Hd * 2;
  unsigned short* wgb = (unsigned short*)(ws);
  unsigned short* wub = (unsigned short*)(ws + WSZ);
  unsigned short* wdb = (unsigned short*)(ws + 2*WSZ);
  unsigned short* xb  = (unsigned short*)(ws + 3*WSZ);
  unsigned short* act = (unsigned short*)(ws + 3*WSZ + (size_t)T_TOK*Hd*2);
  char* misc = ws + 3*WSZ + (size_t)T_TOK*Hd*2 + (size_t)CAPR*Id*2;

  const size_t LOGB = (size_t)T_TOK * NSLOT * 4;
  float* logits = (float*)misc;
  int*   counts  = (int*)(misc + LOGB);
  int*   cursors = counts + 16;
  int*   offsets = cursors + 16;
  char* p2 = misc + LOGB + 256;
  int*   tkid   = (int*)p2;                         p2 += (size_t)T_TOK*TOPK*4;
  float* tkw    = (float*)p2;                       p2 += (size_t)T_TOK*TOPK*4;
  int*   rowmap = (int*)p2;                         p2 += (size_t)CAPR*4;
  float* roww   = (float*)p2;                       p2 += (size_t)CAPR*4;
  int*   tilelist = (int*)p2;                       p2 += (size_t)MAXTILES*4;
  int*   ntiles   = (int*)p2;

  prep_kernel<<<7168, 256, 0, stream>>>(wg, wu, wd, x, wgb, wub, wdb, xb);
  logits_kernel<<<T_TOK/32, 256, 0, stream>>>(x, rw, logits, counts);
  topk_kernel<<<T_TOK/256, 256, 0, stream>>>(logits, bias, x, counts, tkid, tkw, out);
  offsets_kernel<<<1, 64, 0, stream>>>(counts, offsets, cursors, tilelist, ntiles);
  build_kernel<<<CAPR/256, 256, 0, stream>>>(tkid, tkw, offsets, cursors, rowmap, roww);
  gateup_kernel<<<MAXTILES*4, 256, 0, stream>>>(
      xb, wgb, wub, offsets, rowmap, roww, tilelist, ntiles, act);
  down_kernel<<<MAXTILES*8, 256, 0, stream>>>(
      act, wdb, offsets, rowmap, tilelist, ntiles, out);
}

// Round 4
// 377.364 us; speedup vs baseline: 1.3595x; 1.3595x over previous
//
#include <hip/hip_runtime.h>
#include <stdint.h>

#define T_TOK 4096
#define Hd    1024
#define Id    512
#define NE    16
#define NSLOT 32
#define TOPK  4
#define CAPR  (T_TOK*TOPK)
#define MAXTILES 144

typedef __bf16 bf16x8 __attribute__((ext_vector_type(8)));
typedef float  floatx4 __attribute__((ext_vector_type(4)));

#define WAIT_VM(n) asm volatile("s_waitcnt vmcnt(" #n ")" ::: "memory")

static __device__ __forceinline__ void wg_barrier(){
  asm volatile("" ::: "memory");
  __builtin_amdgcn_s_barrier();
  asm volatile("" ::: "memory");
}

static __device__ __forceinline__ unsigned short f2bf(float f){
  unsigned int u = __float_as_uint(f);
  u = u + 0x7fffu + ((u >> 16) & 1u);
  return (unsigned short)(u >> 16);
}

static __device__ __forceinline__ void load_lds16(const void* g, void* l){
  __builtin_amdgcn_global_load_lds((const __attribute__((address_space(1))) void*)g,
                                   (__attribute__((address_space(3))) void*)l, 16, 0, 0);
}

// ---------------- fused prep: x->bf16 + 3 weight transposes ----------------
__global__ __launch_bounds__(256) void prep_kernel(
    const float* __restrict__ wg, const float* __restrict__ wu,
    const float* __restrict__ wd, const float* __restrict__ x,
    unsigned short* __restrict__ wgb, unsigned short* __restrict__ wub,
    unsigned short* __restrict__ wdb, unsigned short* __restrict__ xb){
  __shared__ float tile[64][65];
  const int bid = blockIdx.x;
  const int tid = threadIdx.x;
  if (bid < 6144){
    const float* src; unsigned short* dst; int R, C, cx, ry;
    const int arr = bid >> 11;
    const int rem = bid & 2047;
    const int e = rem >> 7;
    const int r2 = rem & 127;
    if (arr == 0){ src = wg; dst = wgb; R = Hd; C = Id; cx = r2 & 7;  ry = r2 >> 3; }
    else if (arr == 1){ src = wu; dst = wub; R = Hd; C = Id; cx = r2 & 7;  ry = r2 >> 3; }
    else { src = wd; dst = wdb; R = Id; C = Hd; cx = r2 & 15; ry = r2 >> 4; }
    const int c0 = cx * 64, r0 = ry * 64;
    const float* s = src + (size_t)e * R * C;
    unsigned short* d = dst + (size_t)e * R * C;
    const int lr = tid >> 4;
    const int lc = (tid & 15) * 4;
    #pragma unroll
    for (int p = 0; p < 4; ++p){
      int r = p*16 + lr;
      float4 v = *(const float4*)(s + (size_t)(r0 + r)*C + c0 + lc);
      tile[r][lc+0] = v.x; tile[r][lc+1] = v.y; tile[r][lc+2] = v.z; tile[r][lc+3] = v.w;
    }
    __syncthreads();
    #pragma unroll
    for (int p = 0; p < 4; ++p){
      int c = p*16 + lr;
      ushort4 o;
      o.x = f2bf(tile[lc+0][c]); o.y = f2bf(tile[lc+1][c]);
      o.z = f2bf(tile[lc+2][c]); o.w = f2bf(tile[lc+3][c]);
      *(ushort4*)(d + (size_t)(c0 + c)*R + r0 + lc) = o;
    }
  } else {
    const int ib = (bid - 6144) * 1024;
    #pragma unroll
    for (int p = 0; p < 4; ++p){
      int i = ib + p*256 + tid;
      float4 v = ((const float4*)x)[i];
      ushort4 o;
      o.x = f2bf(v.x); o.y = f2bf(v.y); o.z = f2bf(v.z); o.w = f2bf(v.w);
      ((ushort4*)xb)[i] = o;
    }
  }
}

// ---------------- fp32 router logits (atomic-free, full K per block) ----------------
__global__ __launch_bounds__(256) void logits_kernel(const float* __restrict__ x,
    const float* __restrict__ rw, float* __restrict__ logits, int* __restrict__ counts){
  if (blockIdx.x == 0 && threadIdx.x < NE) counts[threadIdx.x] = 0;
  __shared__ float srw[NSLOT][260];
  const int tid = threadIdx.x;
  const int t  = blockIdx.x * 32 + (tid >> 3);
  const int s0 = (tid & 7) * 4;
  float4 acc = {0.f, 0.f, 0.f, 0.f};
  for (int c = 0; c < 4; ++c){
    const int kc = c * 256;
    __syncthreads();
    #pragma unroll
    for (int p = 0; p < 8; ++p){
      int idx = tid + p*256;
      int s = idx >> 6;
      int col = (idx & 63) << 2;
      *(float4*)&srw[s][col] = *(const float4*)(rw + (size_t)s*Hd + kc + col);
    }
    __syncthreads();
    for (int k = 0; k < 256; k += 4){
      float4 xv = *(const float4*)(x + (size_t)t*Hd + kc + k);
      float4 r0 = *(const float4*)&srw[s0+0][k];
      float4 r1 = *(const float4*)&srw[s0+1][k];
      float4 r2 = *(const float4*)&srw[s0+2][k];
      float4 r3 = *(const float4*)&srw[s0+3][k];
      acc.x += xv.x*r0.x + xv.y*r0.y + xv.z*r0.z + xv.w*r0.w;
      acc.y += xv.x*r1.x + xv.y*r1.y + xv.z*r1.z + xv.w*r1.w;
      acc.z += xv.x*r2.x + xv.y*r2.y + xv.z*r2.z + xv.w*r2.w;
      acc.w += xv.x*r3.x + xv.y*r3.y + xv.z*r3.z + xv.w*r3.w;
    }
  }
  *(float4*)(logits + (size_t)t*NSLOT + s0) = acc;
}

// ---------------- softmax + bias + top-4 + (out = zw*x) fused ----------------
__global__ __launch_bounds__(256) void topk_kernel(
    const float* __restrict__ logits, const float* __restrict__ bias,
    const float* __restrict__ x,
    int* __restrict__ counts, int* __restrict__ tkid, float* __restrict__ tkw,
    float* __restrict__ out){
  __shared__ float szw[256];
  const int tid = threadIdx.x;
  const int t = blockIdx.x * 256 + tid;
  float sc[32], bsc[32];
  #pragma unroll
  for (int i = 0; i < 32; i += 4){
    float4 v = *(const float4*)(logits + (size_t)t*NSLOT + i);
    sc[i] = v.x; sc[i+1] = v.y; sc[i+2] = v.z; sc[i+3] = v.w;
  }
  float mx = sc[0];
  #pragma unroll
  for (int i = 1; i < 32; ++i) mx = fmaxf(mx, sc[i]);
  float sum = 0.f;
  #pragma unroll
  for (int i = 0; i < 32; ++i){ sc[i] = __expf(sc[i]-mx); sum += sc[i]; }
  float inv = 1.f / sum;
  #pragma unroll
  for (int i = 0; i < 32; ++i){ sc[i] *= inv; bsc[i] = sc[i] + bias[i]; }
  unsigned int chosen = 0;
  float zw = 0.f;
  #pragma unroll
  for (int k = 0; k < TOPK; ++k){
    float bv = -1e30f, bw = 0.f; int best = 0;
    #pragma unroll
    for (int i = 0; i < 32; ++i){
      float v = ((chosen >> i) & 1u) ? -1e30f : bsc[i];
      if (v > bv){ bv = v; best = i; bw = sc[i]; }
    }
    chosen |= (1u << best);
    tkid[t*TOPK + k] = best;
    tkw[t*TOPK + k]  = bw;
    if (best < NE) atomicAdd(&counts[best], 1);
    else zw += bw;
  }
  szw[tid] = zw;
  __syncthreads();
  const int lane = tid & 63, wid = tid >> 6;
  const size_t base = (size_t)blockIdx.x * 256 * Hd;
  for (int r = wid; r < 256; r += 4){
    float s = szw[r];
    const float4* xs = (const float4*)(x + base + (size_t)r*Hd);
    float4* os = (float4*)(out + base + (size_t)r*Hd);
    #pragma unroll
    for (int q = 0; q < 4; ++q){
      float4 v = xs[lane + q*64];
      float4 o; o.x = v.x*s; o.y = v.y*s; o.z = v.z*s; o.w = v.w*s;
      os[lane + q*64] = o;
    }
  }
}

// ---------------- offsets scan + tile list (tiny) ----------------
__global__ void offsets_kernel(const int* __restrict__ counts,
                               int* __restrict__ offsets, int* __restrict__ cursors,
                               int* __restrict__ tilelist, int* __restrict__ ntiles){
  if (threadIdx.x == 0){
    int acc = 0;
    for (int e = 0; e < NE; ++e){ offsets[e] = acc; acc += counts[e]; }
    offsets[NE] = acc;
    int n = 0;
    for (int e = 0; e < NE; ++e){
      int ne = counts[e];
      for (int m = 0; m*128 < ne; ++m) tilelist[n++] = (e << 16) | m;
    }
    ntiles[0] = n;
  }
  if (threadIdx.x < NE) cursors[threadIdx.x] = 0;
}

// ---------------- build compact per-expert row lists ----------------
__global__ __launch_bounds__(256) void build_kernel(
    const int* __restrict__ tkid, const float* __restrict__ tkw,
    const int* __restrict__ offsets, int* __restrict__ cursors,
    int* __restrict__ rowmap, float* __restrict__ roww){
  int i = blockIdx.x * 256 + threadIdx.x;
  int id = tkid[i];
  if (id < NE){
    int pos = atomicAdd(&cursors[id], 1);
    int row = offsets[id] + pos;
    rowmap[row] = i >> 2;
    roww[row]   = tkw[i];
  }
}

// ---------------- fused gate+up GEMM + SwiGLU (128x128, dbuf, tile-list) ----------------
// launch_bounds(256,2): unified VGPR+AGPR need ~220 regs/wave (128 AGPR acc + ~90 VGPR).
// Cap at 2 waves/SIMD = 256 regs -> fits. At 3 waves/SIMD cap=170 -> accumulators SPILL
// to scratch (round-3: WRITE_SIZE 243MB, 6x regression). Do not raise.
__global__ __launch_bounds__(256, 2) void gateup_kernel(
    const unsigned short* __restrict__ xb,
    const unsigned short* __restrict__ wgb,
    const unsigned short* __restrict__ wub,
    const int* __restrict__ offsets,
    const int* __restrict__ rowmap,
    const float* __restrict__ roww,
    const int* __restrict__ tilelist,
    const int* __restrict__ ntiles,
    unsigned short* __restrict__ act){
  const int b = blockIdx.x;
  const int tile = b >> 2;
  if (tile >= ntiles[0]) return;
  const int packed = tilelist[tile];
  const int e  = packed >> 16;
  const int m0 = (packed & 0xffff) * 128;
  const int n0 = (b & 3) * 128;
  const int off = offsets[e];
  const int ne  = offsets[e+1] - off;

  __shared__ unsigned short sA [2][128*32];
  __shared__ unsigned short sBg[2][128*32];
  __shared__ unsigned short sBu[2][128*32];
  __shared__ int sT[128];

  const int tid  = threadIdx.x;
  const int lane = tid & 63;
  const int wid  = tid >> 6;

  if (tid < 128){
    int r = m0 + tid;
    sT[tid] = rowmap[off + ((r < ne) ? r : 0)];
  }
  __syncthreads();

  const int r_in = lane >> 2;
  const int seg  = lane & 3;
  const int rt0  = wid*32 + r_in;
  const int rt1  = rt0 + 16;
  const size_t wbase = (size_t)e * Id * Hd;

  const unsigned short* pA0 = xb + (size_t)sT[rt0]*Hd + seg*8;
  const unsigned short* pA1 = xb + (size_t)sT[rt1]*Hd + seg*8;
  const unsigned short* pG0 = wgb + wbase + (size_t)(n0+rt0)*Hd + seg*8;
  const unsigned short* pG1 = wgb + wbase + (size_t)(n0+rt1)*Hd + seg*8;
  const unsigned short* pU0 = wub + wbase + (size_t)(n0+rt0)*Hd + seg*8;
  const unsigned short* pU1 = wub + wbase + (size_t)(n0+rt1)*Hd + seg*8;
  const int dA0 = wid*1024;
  const int dA1 = wid*1024 + 512;

  floatx4 accg[4][4], accu[4][4];
  #pragma unroll
  for (int i = 0; i < 4; ++i)
    #pragma unroll
    for (int j = 0; j < 4; ++j){
      floatx4 z = {0.f,0.f,0.f,0.f};
      accg[i][j] = z; accu[i][j] = z;
    }

  const int wm = (wid & 1) * 64;
  const int wn = (wid >> 1) * 64;
  const int fm = lane & 15;
  const int fq = lane >> 4;

  load_lds16(pA0, &sA[0][dA0]);  load_lds16(pA1, &sA[0][dA1]);
  load_lds16(pG0, &sBg[0][dA0]); load_lds16(pG1, &sBg[0][dA1]);
  load_lds16(pU0, &sBu[0][dA0]); load_lds16(pU1, &sBu[0][dA1]);

  #pragma unroll 2
  for (int kit = 0; kit < 32; ++kit){
    const int cur = kit & 1;
    if (kit < 31){
      const int nk = (kit+1)*32;
      const int nb = 1 - cur;
      load_lds16(pA0 + nk, &sA[nb][dA0]);  load_lds16(pA1 + nk, &sA[nb][dA1]);
      load_lds16(pG0 + nk, &sBg[nb][dA0]); load_lds16(pG1 + nk, &sBg[nb][dA1]);
      load_lds16(pU0 + nk, &sBu[nb][dA0]); load_lds16(pU1 + nk, &sBu[nb][dA1]);
      WAIT_VM(6);
    } else {
      WAIT_VM(0);
    }
    wg_barrier();
    bf16x8 av[4], bgv[4], buv[4];
    #pragma unroll
    for (int i = 0; i < 4; ++i)
      av[i] = *(const bf16x8*)(&sA[cur][(wm + i*16 + fm)*32 + fq*8]);
    #pragma unroll
    for (int j = 0; j < 4; ++j){
      bgv[j] = *(const bf16x8*)(&sBg[cur][(wn + j*16 + fm)*32 + fq*8]);
      buv[j] = *(const bf16x8*)(&sBu[cur][(wn + j*16 + fm)*32 + fq*8]);
    }
    #pragma unroll
    for (int i = 0; i < 4; ++i)
      #pragma unroll
      for (int j = 0; j < 4; ++j){
        accg[i][j] = __builtin_amdgcn_mfma_f32_16x16x32_bf16(av[i], bgv[j], accg[i][j], 0, 0, 0);
        accu[i][j] = __builtin_amdgcn_mfma_f32_16x16x32_bf16(av[i], buv[j], accu[i][j], 0, 0, 0);
      }
    wg_barrier();
  }

  #pragma unroll
  for (int i = 0; i < 4; ++i){
    #pragma unroll
    for (int r = 0; r < 4; ++r){
      int row = wm + i*16 + fq*4 + r;
      if (m0 + row < ne){
        float w = roww[off + m0 + row];
        size_t rb = (size_t)(off + m0 + row) * Id + n0;
        #pragma unroll
        for (int j = 0; j < 4; ++j){
          float g = accg[i][j][r];
          float u = accu[i][j][r];
          float a = (g / (1.f + __expf(-g))) * u * w;
          act[rb + wn + j*16 + fm] = f2bf(a);
        }
      }
    }
  }
}

// ---------------- down GEMM + atomic scatter (dbuf, tile-list) ----------------
// (256,4): 64 AGPR acc + ~60 VGPR = 124 <= 512/4 = 128 cap -> no spill.
__global__ __launch_bounds__(256, 4) void down_kernel(
    const unsigned short* __restrict__ act,
    const unsigned short* __restrict__ wdb,
    const int* __restrict__ offsets,
    const int* __restrict__ rowmap,
    const int* __restrict__ tilelist,
    const int* __restrict__ ntiles,
    float* __restrict__ out){
  const int b = blockIdx.x;
  const int tile = b >> 3;
  if (tile >= ntiles[0]) return;
  const int packed = tilelist[tile];
  const int e  = packed >> 16;
  const int m0 = (packed & 0xffff) * 128;
  const int n0 = (b & 7) * 128;
  const int off = offsets[e];
  const int ne  = offsets[e+1] - off;

  __shared__ unsigned short sA[2][128*32];
  __shared__ unsigned short sB[2][128*32];
  __shared__ int sT[128];

  const int tid  = threadIdx.x;
  const int lane = tid & 63;
  const int wid  = tid >> 6;
  if (tid < 128){
    int r = m0 + tid;
    sT[tid] = (r < ne) ? rowmap[off + r] : 0;
  }

  const int r_in = lane >> 2, seg = lane & 3;
  const int rt0 = wid*32 + r_in;
  const int rt1 = rt0 + 16;
  const int gr0 = off + ((m0 + rt0 < ne) ? (m0 + rt0) : 0);
  const int gr1 = off + ((m0 + rt1 < ne) ? (m0 + rt1) : 0);
  const size_t wbase = (size_t)e * Hd * Id;
  const unsigned short* pA0 = act + (size_t)gr0*Id + seg*8;
  const unsigned short* pA1 = act + (size_t)gr1*Id + seg*8;
  const unsigned short* pB0 = wdb + wbase + (size_t)(n0+rt0)*Id + seg*8;
  const unsigned short* pB1 = wdb + wbase + (size_t)(n0+rt1)*Id + seg*8;
  const int dA0 = wid*1024, dA1 = wid*1024 + 512;

  floatx4 acc[4][4];
  #pragma unroll
  for (int i = 0; i < 4; ++i)
    #pragma unroll
    for (int j = 0; j < 4; ++j){ floatx4 z = {0.f,0.f,0.f,0.f}; acc[i][j] = z; }

  const int wm = (wid & 1) * 64, wn = (wid >> 1) * 64;
  const int fm = lane & 15, fq = lane >> 4;

  load_lds16(pA0, &sA[0][dA0]); load_lds16(pA1, &sA[0][dA1]);
  load_lds16(pB0, &sB[0][dA0]); load_lds16(pB1, &sB[0][dA1]);

  #pragma unroll 2
  for (int kit = 0; kit < 16; ++kit){
    const int cur = kit & 1;
    if (kit < 15){
      const int nk = (kit+1)*32;
      const int nb = 1 - cur;
      load_lds16(pA0 + nk, &sA[nb][dA0]); load_lds16(pA1 + nk, &sA[nb][dA1]);
      load_lds16(pB0 + nk, &sB[nb][dA0]); load_lds16(pB1 + nk, &sB[nb][dA1]);
      WAIT_VM(4);
    } else {
      WAIT_VM(0);
    }
    wg_barrier();
    bf16x8 av[4], bv[4];
    #pragma unroll
    for (int i = 0; i < 4; ++i) av[i] = *(const bf16x8*)(&sA[cur][(wm + i*16 + fm)*32 + fq*8]);
    #pragma unroll
    for (int j = 0; j < 4; ++j) bv[j] = *(const bf16x8*)(&sB[cur][(wn + j*16 + fm)*32 + fq*8]);
    #pragma unroll
    for (int i = 0; i < 4; ++i)
      #pragma unroll
      for (int j = 0; j < 4; ++j)
        acc[i][j] = __builtin_amdgcn_mfma_f32_16x16x32_bf16(av[i], bv[j], acc[i][j], 0, 0, 0);
    wg_barrier();
  }

  #pragma unroll
  for (int i = 0; i < 4; ++i){
    #pragma unroll
    for (int r = 0; r < 4; ++r){
      int row = wm + i*16 + fq*4 + r;
      if (m0 + row < ne){
        int t = sT[row];
        #pragma unroll
        for (int j = 0; j < 4; ++j)
          atomicAdd(&out[(size_t)t*Hd + n0 + wn + j*16 + fm], acc[i][j][r]);
      }
    }
  }
}

// =================================================================
extern "C" void kernel_launch(void* const* d_in, const int* in_sizes, int n_in,
                              void* d_out, int out_size, void* d_ws, size_t ws_size,
                              hipStream_t stream){
  (void)in_sizes; (void)n_in; (void)out_size; (void)ws_size;
  const float* x    = (const float*)d_in[0];
  const float* rw   = (const float*)d_in[1];
  const float* bias = (const float*)d_in[2];
  const float* wg   = (const float*)d_in[3];
  const float* wu   = (const float*)d_in[4];
  const float* wd   = (const float*)d_in[5];
  float* out = (float*)d_out;

  char* ws = (char*)d_ws;
  const size_t WSZ = (size_t)NE * Id * Hd * 2;
  unsigned short* wgb = (unsigned short*)(ws);
  unsigned short* wub = (unsigned short*)(ws + WSZ);
  unsigned short* wdb = (unsigned short*)(ws + 2*WSZ);
  unsigned short* xb  = (unsigned short*)(ws + 3*WSZ);
  unsigned short* act = (unsigned short*)(ws + 3*WSZ + (size_t)T_TOK*Hd*2);
  char* misc = ws + 3*WSZ + (size_t)T_TOK*Hd*2 + (size_t)CAPR*Id*2;

  const size_t LOGB = (size_t)T_TOK * NSLOT * 4;
  float* logits = (float*)misc;
  int*   counts  = (int*)(misc + LOGB);
  int*   cursors = counts + 16;
  int*   offsets = cursors + 16;
  char* p2 = misc + LOGB + 256;
  int*   tkid   = (int*)p2;                         p2 += (size_t)T_TOK*TOPK*4;
  float* tkw    = (float*)p2;                       p2 += (size_t)T_TOK*TOPK*4;
  int*   rowmap = (int*)p2;                         p2 += (size_t)CAPR*4;
  float* roww   = (float*)p2;                       p2 += (size_t)CAPR*4;
  int*   tilelist = (int*)p2;                       p2 += (size_t)MAXTILES*4;
  int*   ntiles   = (int*)p2;

  prep_kernel<<<7168, 256, 0, stream>>>(wg, wu, wd, x, wgb, wub, wdb, xb);
  logits_kernel<<<T_TOK/32, 256, 0, stream>>>(x, rw, logits, counts);
  topk_kernel<<<T_TOK/256, 256, 0, stream>>>(logits, bias, x, counts, tkid, tkw, out);
  offsets_kernel<<<1, 64, 0, stream>>>(counts, offsets, cursors, tilelist, ntiles);
  build_kernel<<<CAPR/256, 256, 0, stream>>>(tkid, tkw, offsets, cursors, rowmap, roww);
  gateup_kernel<<<MAXTILES*4, 256, 0, stream>>>(
      xb, wgb, wub, offsets, rowmap, roww, tilelist, ntiles, act);
  down_kernel<<<MAXTILES*8, 256, 0, stream>>>(
      act, wdb, offsets, rowmap, tilelist, ntiles, out);
}

// Round 5
// 322.358 us; speedup vs baseline: 1.5915x; 1.1706x over previous
//
#include <hip/hip_runtime.h>
#include <stdint.h>

#define T_TOK 4096
#define Hd    1024
#define Id    512
#define NE    16
#define NSLOT 32
#define TOPK  4
#define CAPR  (T_TOK*TOPK)
#define MAXTILES 144

typedef __bf16 bf16x8 __attribute__((ext_vector_type(8)));
typedef float  floatx4 __attribute__((ext_vector_type(4)));

#define WAIT_VM(n) asm volatile("s_waitcnt vmcnt(" #n ")" ::: "memory")

static __device__ __forceinline__ void wg_barrier(){
  asm volatile("" ::: "memory");
  __builtin_amdgcn_s_barrier();
  asm volatile("" ::: "memory");
}

static __device__ __forceinline__ unsigned short f2bf(float f){
  unsigned int u = __float_as_uint(f);
  u = u + 0x7fffu + ((u >> 16) & 1u);
  return (unsigned short)(u >> 16);
}

static __device__ __forceinline__ void load_lds16(const void* g, void* l){
  __builtin_amdgcn_global_load_lds((const __attribute__((address_space(1))) void*)g,
                                   (__attribute__((address_space(3))) void*)l, 16, 0, 0);
}

// Branch-free local prefix over counts[0..id): no indexed local array (scratch-safe).
static __device__ __forceinline__ int prefix_before(const int* __restrict__ counts, int id){
  int off = 0;
  #pragma unroll
  for (int ee = 0; ee < NE; ++ee) off += (ee < id) ? counts[ee] : 0;
  return off;
}

// ---------------- fused prep: x->bf16 + 3 weight transposes + router logits ----------------
// blocks [0,6144): transpose-convert; [6144,7168): x cvt; [7168,7296): logits
__global__ __launch_bounds__(256) void prep_kernel(
    const float* __restrict__ wg, const float* __restrict__ wu,
    const float* __restrict__ wd, const float* __restrict__ x,
    const float* __restrict__ rw,
    unsigned short* __restrict__ wgb, unsigned short* __restrict__ wub,
    unsigned short* __restrict__ wdb, unsigned short* __restrict__ xb,
    float* __restrict__ logits, int* __restrict__ counts, int* __restrict__ cursors){
  __shared__ float shbuf[NSLOT*260];     // logits: srw[32][260]; transpose aliases [64][65]
  const int bid = blockIdx.x;
  const int tid = threadIdx.x;
  if (bid < 6144){
    float* tile = shbuf;                 // [64][65]
    const float* src; unsigned short* dst; int R, C, cx, ry;
    const int arr = bid >> 11;
    const int rem = bid & 2047;
    const int e = rem >> 7;
    const int r2 = rem & 127;
    if (arr == 0){ src = wg; dst = wgb; R = Hd; C = Id; cx = r2 & 7;  ry = r2 >> 3; }
    else if (arr == 1){ src = wu; dst = wub; R = Hd; C = Id; cx = r2 & 7;  ry = r2 >> 3; }
    else { src = wd; dst = wdb; R = Id; C = Hd; cx = r2 & 15; ry = r2 >> 4; }
    const int c0 = cx * 64, r0 = ry * 64;
    const float* s = src + (size_t)e * R * C;
    unsigned short* d = dst + (size_t)e * R * C;
    const int lr = tid >> 4;
    const int lc = (tid & 15) * 4;
    #pragma unroll
    for (int p = 0; p < 4; ++p){
      int r = p*16 + lr;
      float4 v = *(const float4*)(s + (size_t)(r0 + r)*C + c0 + lc);
      tile[r*65 + lc+0] = v.x; tile[r*65 + lc+1] = v.y;
      tile[r*65 + lc+2] = v.z; tile[r*65 + lc+3] = v.w;
    }
    __syncthreads();
    #pragma unroll
    for (int p = 0; p < 4; ++p){
      int c = p*16 + lr;
      ushort4 o;
      o.x = f2bf(tile[(lc+0)*65 + c]); o.y = f2bf(tile[(lc+1)*65 + c]);
      o.z = f2bf(tile[(lc+2)*65 + c]); o.w = f2bf(tile[(lc+3)*65 + c]);
      *(ushort4*)(d + (size_t)(c0 + c)*R + r0 + lc) = o;
    }
  } else if (bid < 7168){
    const int ib = (bid - 6144) * 1024;
    #pragma unroll
    for (int p = 0; p < 4; ++p){
      int i = ib + p*256 + tid;
      float4 v = ((const float4*)x)[i];
      ushort4 o;
      o.x = f2bf(v.x); o.y = f2bf(v.y); o.z = f2bf(v.z); o.w = f2bf(v.w);
      ((ushort4*)xb)[i] = o;
    }
  } else {
    if (bid == 7168 && tid < 2*NE){      // zero counts+cursors (contiguous)
      counts[tid] = 0;
    }
    float* srw = shbuf;                  // [32][260]
    const int lb = bid - 7168;
    const int t  = lb * 32 + (tid >> 3);
    const int s0 = (tid & 7) * 4;
    float4 acc = {0.f, 0.f, 0.f, 0.f};
    for (int c = 0; c < 4; ++c){
      const int kc = c * 256;
      __syncthreads();
      #pragma unroll
      for (int p = 0; p < 8; ++p){
        int idx = tid + p*256;
        int s = idx >> 6;
        int col = (idx & 63) << 2;
        *(float4*)&srw[s*260 + col] = *(const float4*)(rw + (size_t)s*Hd + kc + col);
      }
      __syncthreads();
      for (int k = 0; k < 256; k += 4){
        float4 xv = *(const float4*)(x + (size_t)t*Hd + kc + k);
        float4 r0 = *(const float4*)&srw[(s0+0)*260 + k];
        float4 r1 = *(const float4*)&srw[(s0+1)*260 + k];
        float4 r2 = *(const float4*)&srw[(s0+2)*260 + k];
        float4 r3 = *(const float4*)&srw[(s0+3)*260 + k];
        acc.x += xv.x*r0.x + xv.y*r0.y + xv.z*r0.z + xv.w*r0.w;
        acc.y += xv.x*r1.x + xv.y*r1.y + xv.z*r1.z + xv.w*r1.w;
        acc.z += xv.x*r2.x + xv.y*r2.y + xv.z*r2.z + xv.w*r2.w;
        acc.w += xv.x*r3.x + xv.y*r3.y + xv.z*r3.z + xv.w*r3.w;
      }
    }
    *(float4*)(logits + (size_t)t*NSLOT + s0) = acc;
  }
}

// ---------------- softmax + bias + top-4 + (out = zw*x), 8 tokens/block ----------------
__global__ __launch_bounds__(256) void topk_kernel(
    const float* __restrict__ logits, const float* __restrict__ bias,
    const float* __restrict__ x,
    int* __restrict__ counts, int* __restrict__ tkid, float* __restrict__ tkw,
    float* __restrict__ out){
  __shared__ float szw[8];
  const int tid = threadIdx.x;
  if (tid < 8){
    const int t = blockIdx.x * 8 + tid;
    float sc[32], bsc[32];
    #pragma unroll
    for (int i = 0; i < 32; i += 4){
      float4 v = *(const float4*)(logits + (size_t)t*NSLOT + i);
      sc[i] = v.x; sc[i+1] = v.y; sc[i+2] = v.z; sc[i+3] = v.w;
    }
    float mx = sc[0];
    #pragma unroll
    for (int i = 1; i < 32; ++i) mx = fmaxf(mx, sc[i]);
    float sum = 0.f;
    #pragma unroll
    for (int i = 0; i < 32; ++i){ sc[i] = __expf(sc[i]-mx); sum += sc[i]; }
    float inv = 1.f / sum;
    #pragma unroll
    for (int i = 0; i < 32; ++i){ sc[i] *= inv; bsc[i] = sc[i] + bias[i]; }
    unsigned int chosen = 0;
    float zw = 0.f;
    #pragma unroll
    for (int k = 0; k < TOPK; ++k){
      float bv = -1e30f, bw = 0.f; int best = 0;
      #pragma unroll
      for (int i = 0; i < 32; ++i){
        float v = ((chosen >> i) & 1u) ? -1e30f : bsc[i];
        if (v > bv){ bv = v; best = i; bw = sc[i]; }
      }
      chosen |= (1u << best);
      tkid[t*TOPK + k] = best;
      tkw[t*TOPK + k]  = bw;
      if (best < NE) atomicAdd(&counts[best], 1);
      else zw += bw;
    }
    szw[tid] = zw;
  }
  __syncthreads();
  const int lane = tid & 63, wid = tid >> 6;
  const size_t base = (size_t)blockIdx.x * 8 * Hd;
  #pragma unroll
  for (int r0 = 0; r0 < 8; r0 += 4){
    int r = r0 + wid;
    float s = szw[r];
    const float4* xs = (const float4*)(x + base + (size_t)r*Hd);
    float4* os = (float4*)(out + base + (size_t)r*Hd);
    #pragma unroll
    for (int q = 0; q < 4; ++q){
      float4 v = xs[lane + q*64];
      float4 o; o.x = v.x*s; o.y = v.y*s; o.z = v.z*s; o.w = v.w*s;
      os[lane + q*64] = o;
    }
  }
}

// ---------------- build compact per-expert row lists (local prefix) ----------------
__global__ __launch_bounds__(256) void build_kernel(
    const int* __restrict__ tkid, const float* __restrict__ tkw,
    const int* __restrict__ counts, int* __restrict__ cursors,
    int* __restrict__ rowmap, float* __restrict__ roww){
  int i = blockIdx.x * 256 + threadIdx.x;
  int id = tkid[i];
  if (id < NE){
    int offe = prefix_before(counts, id);
    int pos = atomicAdd(&cursors[id], 1);
    rowmap[offe + pos] = i >> 2;
    roww[offe + pos]   = tkw[i];
  }
}

// Map linear tile index -> (expert e, row offset off, rows ne, m0). Returns false if OOR.
static __device__ __forceinline__ bool tile_map(const int* __restrict__ counts, int tile,
                                                int& e, int& off, int& ne, int& m0){
  int cumT = 0, o = 0; e = -1; ne = 0; m0 = 0; off = 0;
  #pragma unroll
  for (int ee = 0; ee < NE; ++ee){
    int c = counts[ee];
    int nt = (c + 127) >> 7;
    bool here = (e < 0) && (tile < cumT + nt);
    if (here){ e = ee; ne = c; m0 = (tile - cumT) * 128; off = o; }
    if (e < 0) o += c;
    cumT += nt;
  }
  return e >= 0;
}

// ---------------- fused gate+up GEMM + SwiGLU (128x128, dbuf) ----------------
// (256,2): 128 AGPR acc + ~90 VGPR ~ 220 regs/wave; 3 waves/SIMD cap=170 -> SPILLS
// (round-3 regression: WRITE_SIZE 243MB). Do not raise.
__global__ __launch_bounds__(256, 2) void gateup_kernel(
    const unsigned short* __restrict__ xb,
    const unsigned short* __restrict__ wgb,
    const unsigned short* __restrict__ wub,
    const int* __restrict__ counts,
    const int* __restrict__ rowmap,
    const float* __restrict__ roww,
    unsigned short* __restrict__ act){
  const int b = blockIdx.x;
  int e, off, ne, m0;
  if (!tile_map(counts, b >> 2, e, off, ne, m0)) return;
  const int n0 = (b & 3) * 128;

  __shared__ unsigned short sA [2][128*32];
  __shared__ unsigned short sBg[2][128*32];
  __shared__ unsigned short sBu[2][128*32];
  __shared__ int sT[128];

  const int tid  = threadIdx.x;
  const int lane = tid & 63;
  const int wid  = tid >> 6;

  if (tid < 128){
    int r = m0 + tid;
    sT[tid] = rowmap[off + ((r < ne) ? r : 0)];
  }
  __syncthreads();

  const int r_in = lane >> 2;
  const int seg  = lane & 3;
  const int rt0  = wid*32 + r_in;
  const int rt1  = rt0 + 16;
  const size_t wbase = (size_t)e * Id * Hd;

  const unsigned short* pA0 = xb + (size_t)sT[rt0]*Hd + seg*8;
  const unsigned short* pA1 = xb + (size_t)sT[rt1]*Hd + seg*8;
  const unsigned short* pG0 = wgb + wbase + (size_t)(n0+rt0)*Hd + seg*8;
  const unsigned short* pG1 = wgb + wbase + (size_t)(n0+rt1)*Hd + seg*8;
  const unsigned short* pU0 = wub + wbase + (size_t)(n0+rt0)*Hd + seg*8;
  const unsigned short* pU1 = wub + wbase + (size_t)(n0+rt1)*Hd + seg*8;
  const int dA0 = wid*1024;
  const int dA1 = wid*1024 + 512;

  floatx4 accg[4][4], accu[4][4];
  #pragma unroll
  for (int i = 0; i < 4; ++i)
    #pragma unroll
    for (int j = 0; j < 4; ++j){
      floatx4 z = {0.f,0.f,0.f,0.f};
      accg[i][j] = z; accu[i][j] = z;
    }

  const int wm = (wid & 1) * 64;
  const int wn = (wid >> 1) * 64;
  const int fm = lane & 15;
  const int fq = lane >> 4;

  load_lds16(pA0, &sA[0][dA0]);  load_lds16(pA1, &sA[0][dA1]);
  load_lds16(pG0, &sBg[0][dA0]); load_lds16(pG1, &sBg[0][dA1]);
  load_lds16(pU0, &sBu[0][dA0]); load_lds16(pU1, &sBu[0][dA1]);

  #pragma unroll 2
  for (int kit = 0; kit < 32; ++kit){
    const int cur = kit & 1;
    if (kit < 31){
      const int nk = (kit+1)*32;
      const int nb = 1 - cur;
      load_lds16(pA0 + nk, &sA[nb][dA0]);  load_lds16(pA1 + nk, &sA[nb][dA1]);
      load_lds16(pG0 + nk, &sBg[nb][dA0]); load_lds16(pG1 + nk, &sBg[nb][dA1]);
      load_lds16(pU0 + nk, &sBu[nb][dA0]); load_lds16(pU1 + nk, &sBu[nb][dA1]);
      WAIT_VM(6);
    } else {
      WAIT_VM(0);
    }
    wg_barrier();
    bf16x8 av[4], bgv[4], buv[4];
    #pragma unroll
    for (int i = 0; i < 4; ++i)
      av[i] = *(const bf16x8*)(&sA[cur][(wm + i*16 + fm)*32 + fq*8]);
    #pragma unroll
    for (int j = 0; j < 4; ++j){
      bgv[j] = *(const bf16x8*)(&sBg[cur][(wn + j*16 + fm)*32 + fq*8]);
      buv[j] = *(const bf16x8*)(&sBu[cur][(wn + j*16 + fm)*32 + fq*8]);
    }
    #pragma unroll
    for (int i = 0; i < 4; ++i)
      #pragma unroll
      for (int j = 0; j < 4; ++j){
        accg[i][j] = __builtin_amdgcn_mfma_f32_16x16x32_bf16(av[i], bgv[j], accg[i][j], 0, 0, 0);
        accu[i][j] = __builtin_amdgcn_mfma_f32_16x16x32_bf16(av[i], buv[j], accu[i][j], 0, 0, 0);
      }
    wg_barrier();
  }

  #pragma unroll
  for (int i = 0; i < 4; ++i){
    #pragma unroll
    for (int r = 0; r < 4; ++r){
      int row = wm + i*16 + fq*4 + r;
      if (m0 + row < ne){
        float w = roww[off + m0 + row];
        size_t rb = (size_t)(off + m0 + row) * Id + n0;
        #pragma unroll
        for (int j = 0; j < 4; ++j){
          float g = accg[i][j][r];
          float u = accu[i][j][r];
          float a = (g / (1.f + __expf(-g))) * u * w;
          act[rb + wn + j*16 + fm] = f2bf(a);
        }
      }
    }
  }
}

// ---------------- down GEMM + atomic scatter (dbuf) ----------------
// (256,4): 64 AGPR acc + ~60 VGPR = 124 <= 128 cap -> no spill.
__global__ __launch_bounds__(256, 4) void down_kernel(
    const unsigned short* __restrict__ act,
    const unsigned short* __restrict__ wdb,
    const int* __restrict__ counts,
    const int* __restrict__ rowmap,
    float* __restrict__ out){
  const int b = blockIdx.x;
  int e, off, ne, m0;
  if (!tile_map(counts, b >> 3, e, off, ne, m0)) return;
  const int n0 = (b & 7) * 128;

  __shared__ unsigned short sA[2][128*32];
  __shared__ unsigned short sB[2][128*32];
  __shared__ int sT[128];

  const int tid  = threadIdx.x;
  const int lane = tid & 63;
  const int wid  = tid >> 6;
  if (tid < 128){
    int r = m0 + tid;
    sT[tid] = (r < ne) ? rowmap[off + r] : 0;
  }

  const int r_in = lane >> 2, seg = lane & 3;
  const int rt0 = wid*32 + r_in;
  const int rt1 = rt0 + 16;
  const int gr0 = off + ((m0 + rt0 < ne) ? (m0 + rt0) : 0);
  const int gr1 = off + ((m0 + rt1 < ne) ? (m0 + rt1) : 0);
  const size_t wbase = (size_t)e * Hd * Id;
  const unsigned short* pA0 = act + (size_t)gr0*Id + seg*8;
  const unsigned short* pA1 = act + (size_t)gr1*Id + seg*8;
  const unsigned short* pB0 = wdb + wbase + (size_t)(n0+rt0)*Id + seg*8;
  const unsigned short* pB1 = wdb + wbase + (size_t)(n0+rt1)*Id + seg*8;
  const int dA0 = wid*1024, dA1 = wid*1024 + 512;

  floatx4 acc[4][4];
  #pragma unroll
  for (int i = 0; i < 4; ++i)
    #pragma unroll
    for (int j = 0; j < 4; ++j){ floatx4 z = {0.f,0.f,0.f,0.f}; acc[i][j] = z; }

  const int wm = (wid & 1) * 64, wn = (wid >> 1) * 64;
  const int fm = lane & 15, fq = lane >> 4;

  load_lds16(pA0, &sA[0][dA0]); load_lds16(pA1, &sA[0][dA1]);
  load_lds16(pB0, &sB[0][dA0]); load_lds16(pB1, &sB[0][dA1]);

  #pragma unroll 2
  for (int kit = 0; kit < 16; ++kit){
    const int cur = kit & 1;
    if (kit < 15){
      const int nk = (kit+1)*32;
      const int nb = 1 - cur;
      load_lds16(pA0 + nk, &sA[nb][dA0]); load_lds16(pA1 + nk, &sA[nb][dA1]);
      load_lds16(pB0 + nk, &sB[nb][dA0]); load_lds16(pB1 + nk, &sB[nb][dA1]);
      WAIT_VM(4);
    } else {
      WAIT_VM(0);
    }
    wg_barrier();
    bf16x8 av[4], bv[4];
    #pragma unroll
    for (int i = 0; i < 4; ++i) av[i] = *(const bf16x8*)(&sA[cur][(wm + i*16 + fm)*32 + fq*8]);
    #pragma unroll
    for (int j = 0; j < 4; ++j) bv[j] = *(const bf16x8*)(&sB[cur][(wn + j*16 + fm)*32 + fq*8]);
    #pragma unroll
    for (int i = 0; i < 4; ++i)
      #pragma unroll
      for (int j = 0; j < 4; ++j)
        acc[i][j] = __builtin_amdgcn_mfma_f32_16x16x32_bf16(av[i], bv[j], acc[i][j], 0, 0, 0);
    wg_barrier();
  }

  #pragma unroll
  for (int i = 0; i < 4; ++i){
    #pragma unroll
    for (int r = 0; r < 4; ++r){
      int row = wm + i*16 + fq*4 + r;
      if (m0 + row < ne){
        int t = sT[row];
        #pragma unroll
        for (int j = 0; j < 4; ++j)
          atomicAdd(&out[(size_t)t*Hd + n0 + wn + j*16 + fm], acc[i][j][r]);
      }
    }
  }
}

// =================================================================
extern "C" void kernel_launch(void* const* d_in, const int* in_sizes, int n_in,
                              void* d_out, int out_size, void* d_ws, size_t ws_size,
                              hipStream_t stream){
  (void)in_sizes; (void)n_in; (void)out_size; (void)ws_size;
  const float* x    = (const float*)d_in[0];
  const float* rw   = (const float*)d_in[1];
  const float* bias = (const float*)d_in[2];
  const float* wg   = (const float*)d_in[3];
  const float* wu   = (const float*)d_in[4];
  const float* wd   = (const float*)d_in[5];
  float* out = (float*)d_out;

  char* ws = (char*)d_ws;
  const size_t WSZ = (size_t)NE * Id * Hd * 2;
  unsigned short* wgb = (unsigned short*)(ws);
  unsigned short* wub = (unsigned short*)(ws + WSZ);
  unsigned short* wdb = (unsigned short*)(ws + 2*WSZ);
  unsigned short* xb  = (unsigned short*)(ws + 3*WSZ);
  unsigned short* act = (unsigned short*)(ws + 3*WSZ + (size_t)T_TOK*Hd*2);
  char* misc = ws + 3*WSZ + (size_t)T_TOK*Hd*2 + (size_t)CAPR*Id*2;

  const size_t LOGB = (size_t)T_TOK * NSLOT * 4;
  float* logits  = (float*)misc;
  int*   counts  = (int*)(misc + LOGB);   // [16] then cursors [16] contiguous
  int*   cursors = counts + 16;
  char* p2 = misc + LOGB + 256;
  int*   tkid   = (int*)p2;                p2 += (size_t)T_TOK*TOPK*4;
  float* tkw    = (float*)p2;              p2 += (size_t)T_TOK*TOPK*4;
  int*   rowmap = (int*)p2;                p2 += (size_t)CAPR*4;
  float* roww   = (float*)p2;

  prep_kernel<<<7296, 256, 0, stream>>>(wg, wu, wd, x, rw,
                                        wgb, wub, wdb, xb, logits, counts, cursors);
  topk_kernel<<<T_TOK/8, 256, 0, stream>>>(logits, bias, x, counts, tkid, tkw, out);
  build_kernel<<<CAPR/256, 256, 0, stream>>>(tkid, tkw, counts, cursors, rowmap, roww);
  gateup_kernel<<<MAXTILES*4, 256, 0, stream>>>(xb, wgb, wub, counts, rowmap, roww, act);
  down_kernel<<<MAXTILES*8, 256, 0, stream>>>(act, wdb, counts, rowmap, out);
}

// Round 6
// 304.362 us; speedup vs baseline: 1.6856x; 1.0591x over previous
//
#include <hip/hip_runtime.h>
#include <stdint.h>

#define T_TOK 4096
#define Hd    1024
#define Id    512
#define NE    16
#define NSLOT 32
#define TOPK  4
#define ECAP  1024   // per-expert row capacity; E[count]=512, sigma~21 -> +24 sigma
#define MAXT  (NE * (ECAP/128))   // 128 tiles max

typedef __bf16 bf16x8 __attribute__((ext_vector_type(8)));
typedef float  floatx4 __attribute__((ext_vector_type(4)));

#define WAIT_VM(n) asm volatile("s_waitcnt vmcnt(" #n ")" ::: "memory")

static __device__ __forceinline__ void wg_barrier(){
  asm volatile("" ::: "memory");
  __builtin_amdgcn_s_barrier();
  asm volatile("" ::: "memory");
}

static __device__ __forceinline__ unsigned short f2bf(float f){
  unsigned int u = __float_as_uint(f);
  u = u + 0x7fffu + ((u >> 16) & 1u);
  return (unsigned short)(u >> 16);
}

static __device__ __forceinline__ void load_lds16(const void* g, void* l){
  __builtin_amdgcn_global_load_lds((const __attribute__((address_space(1))) void*)g,
                                   (__attribute__((address_space(3))) void*)l, 16, 0, 0);
}

// ---------------- fused prep: strip transposes + x->bf16 + router logits ----------------
// blocks [0,256): wg strips  [256,512): wu strips  [512,640): wd strips
//        [640,1664): x cvt   [1664,1792): logits (+cursor zero)
__global__ __launch_bounds__(256) void prep_kernel(
    const float* __restrict__ wg, const float* __restrict__ wu,
    const float* __restrict__ wd, const float* __restrict__ x,
    const float* __restrict__ rw,
    unsigned short* __restrict__ wgb, unsigned short* __restrict__ wub,
    unsigned short* __restrict__ wdb, unsigned short* __restrict__ xb,
    float* __restrict__ logits, int* __restrict__ cursors){
  __shared__ float shbuf[2*64*65];      // 33,280B; logits aliases as [32][260] (same size)
  const int bid = blockIdx.x;
  const int tid = threadIdx.x;
  if (bid < 640){
    // ---- strip transpose: src [R][C] fp32 -> dst [C][R] bf16, 64 rows x C cols ----
    const float* src; unsigned short* dst; int R, C, e, r0;
    if (bid < 256)      { src = wg; dst = wgb; R = Hd; C = Id; e = bid >> 4;        r0 = (bid & 15) * 64; }
    else if (bid < 512) { src = wu; dst = wub; R = Hd; C = Id; e = (bid - 256) >> 4; r0 = (bid & 15) * 64; }
    else                { src = wd; dst = wdb; R = Id; C = Hd; e = (bid - 512) >> 3; r0 = ((bid - 512) & 7) * 64; }
    const int J = C >> 6;
    const float* s = src + (size_t)e * R * C + (size_t)r0 * C;
    unsigned short* d = dst + (size_t)e * R * C + r0;
    const int lr = tid >> 4;            // 0..15
    const int lc = (tid & 15) * 4;      // 0..60
    float* b0 = shbuf;
    float* b1 = shbuf + 64*65;
    float4 v[4];
    // prologue: tile 0 -> buf0
    #pragma unroll
    for (int p = 0; p < 4; ++p)
      v[p] = *(const float4*)(s + (size_t)(p*16 + lr)*C + lc);
    #pragma unroll
    for (int p = 0; p < 4; ++p){
      float* row = b0 + (p*16 + lr)*65 + lc;
      row[0] = v[p].x; row[1] = v[p].y; row[2] = v[p].z; row[3] = v[p].w;
    }
    __syncthreads();
    for (int j = 0; j < J; ++j){
      float* cur = (j & 1) ? b1 : b0;
      float* nxt = (j & 1) ? b0 : b1;
      if (j + 1 < J){
        const int c0n = (j + 1) * 64;
        #pragma unroll
        for (int p = 0; p < 4; ++p)
          v[p] = *(const float4*)(s + (size_t)(p*16 + lr)*C + c0n + lc);
      }
      const int c0 = j * 64;
      #pragma unroll
      for (int p = 0; p < 4; ++p){
        int c = p*16 + lr;
        ushort4 o;
        o.x = f2bf(cur[(lc+0)*65 + c]); o.y = f2bf(cur[(lc+1)*65 + c]);
        o.z = f2bf(cur[(lc+2)*65 + c]); o.w = f2bf(cur[(lc+3)*65 + c]);
        *(ushort4*)(d + (size_t)(c0 + c)*R + lc) = o;
      }
      if (j + 1 < J){
        #pragma unroll
        for (int p = 0; p < 4; ++p){
          float* row = nxt + (p*16 + lr)*65 + lc;
          row[0] = v[p].x; row[1] = v[p].y; row[2] = v[p].z; row[3] = v[p].w;
        }
      }
      __syncthreads();
    }
  } else if (bid < 1664){
    // ---- x -> bf16 ----
    const int ib = (bid - 640) * 1024;
    #pragma unroll
    for (int p = 0; p < 4; ++p){
      int i = ib + p*256 + tid;
      float4 v = ((const float4*)x)[i];
      ushort4 o;
      o.x = f2bf(v.x); o.y = f2bf(v.y); o.z = f2bf(v.z); o.w = f2bf(v.w);
      ((ushort4*)xb)[i] = o;
    }
  } else {
    // ---- router logits (fp32). Slot-stride-8 mapping: banks (s*4+k)%32 span all
    // 32 banks across the 8 s0 groups -> conflict-free srw reads.
    const int lb = bid - 1664;
    if (lb == 0 && tid < NE) cursors[tid] = 0;
    float* srw = shbuf;                 // [32][260]
    const int t  = lb * 32 + (tid >> 3);
    const int s0 = tid & 7;
    float4 acc = {0.f, 0.f, 0.f, 0.f};  // slots s0, s0+8, s0+16, s0+24
    for (int c = 0; c < 4; ++c){
      const int kc = c * 256;
      __syncthreads();
      #pragma unroll
      for (int p = 0; p < 8; ++p){
        int idx = tid + p*256;
        int s = idx >> 6;
        int col = (idx & 63) << 2;
        *(float4*)&srw[s*260 + col] = *(const float4*)(rw + (size_t)s*Hd + kc + col);
      }
      __syncthreads();
      for (int k = 0; k < 256; k += 4){
        float4 xv = *(const float4*)(x + (size_t)t*Hd + kc + k);
        float4 r0 = *(const float4*)&srw[(s0+ 0)*260 + k];
        float4 r1 = *(const float4*)&srw[(s0+ 8)*260 + k];
        float4 r2 = *(const float4*)&srw[(s0+16)*260 + k];
        float4 r3 = *(const float4*)&srw[(s0+24)*260 + k];
        acc.x += xv.x*r0.x + xv.y*r0.y + xv.z*r0.z + xv.w*r0.w;
        acc.y += xv.x*r1.x + xv.y*r1.y + xv.z*r1.z + xv.w*r1.w;
        acc.z += xv.x*r2.x + xv.y*r2.y + xv.z*r2.z + xv.w*r2.w;
        acc.w += xv.x*r3.x + xv.y*r3.y + xv.z*r3.z + xv.w*r3.w;
      }
    }
    logits[(size_t)t*NSLOT + s0     ] = acc.x;
    logits[(size_t)t*NSLOT + s0 +  8] = acc.y;
    logits[(size_t)t*NSLOT + s0 + 16] = acc.z;
    logits[(size_t)t*NSLOT + s0 + 24] = acc.w;
  }
}

// ---------------- softmax + bias + top-4 + direct row scatter + (out = zw*x) ----------------
__global__ __launch_bounds__(256) void topk_kernel(
    const float* __restrict__ logits, const float* __restrict__ bias,
    const float* __restrict__ x,
    int* __restrict__ cursors, int* __restrict__ rowmap, float* __restrict__ roww,
    float* __restrict__ out){
  __shared__ float szw[8];
  const int tid = threadIdx.x;
  if (tid < 8){
    const int t = blockIdx.x * 8 + tid;
    float sc[32], bsc[32];
    #pragma unroll
    for (int i = 0; i < 32; i += 4){
      float4 v = *(const float4*)(logits + (size_t)t*NSLOT + i);
      sc[i] = v.x; sc[i+1] = v.y; sc[i+2] = v.z; sc[i+3] = v.w;
    }
    float mx = sc[0];
    #pragma unroll
    for (int i = 1; i < 32; ++i) mx = fmaxf(mx, sc[i]);
    float sum = 0.f;
    #pragma unroll
    for (int i = 0; i < 32; ++i){ sc[i] = __expf(sc[i]-mx); sum += sc[i]; }
    float inv = 1.f / sum;
    #pragma unroll
    for (int i = 0; i < 32; ++i){ sc[i] *= inv; bsc[i] = sc[i] + bias[i]; }
    unsigned int chosen = 0;
    float zw = 0.f;
    #pragma unroll
    for (int k = 0; k < TOPK; ++k){
      float bv = -1e30f, bw = 0.f; int best = 0;
      #pragma unroll
      for (int i = 0; i < 32; ++i){
        float v = ((chosen >> i) & 1u) ? -1e30f : bsc[i];
        if (v > bv){ bv = v; best = i; bw = sc[i]; }
      }
      chosen |= (1u << best);
      if (best < NE){
        int pos = atomicAdd(&cursors[best], 1);
        rowmap[best*ECAP + pos] = t;
        roww[best*ECAP + pos]   = bw;
      } else zw += bw;
    }
    szw[tid] = zw;
  }
  __syncthreads();
  const int lane = tid & 63, wid = tid >> 6;
  const size_t base = (size_t)blockIdx.x * 8 * Hd;
  #pragma unroll
  for (int r0 = 0; r0 < 8; r0 += 4){
    int r = r0 + wid;
    float s = szw[r];
    const float4* xs = (const float4*)(x + base + (size_t)r*Hd);
    float4* os = (float4*)(out + base + (size_t)r*Hd);
    #pragma unroll
    for (int q = 0; q < 4; ++q){
      float4 v = xs[lane + q*64];
      float4 o; o.x = v.x*s; o.y = v.y*s; o.z = v.z*s; o.w = v.w*s;
      os[lane + q*64] = o;
    }
  }
}

// Map linear tile -> (expert, row-base e*ECAP, rows ne, m0). False if out of range.
static __device__ __forceinline__ bool tile_map(const int* __restrict__ counts, int tile,
                                                int& e, int& off, int& ne, int& m0){
  int cumT = 0; e = -1; ne = 0; m0 = 0;
  #pragma unroll
  for (int ee = 0; ee < NE; ++ee){
    int c = counts[ee];
    int nt = (c + 127) >> 7;
    bool here = (e < 0) && (tile < cumT + nt);
    if (here){ e = ee; ne = c; m0 = (tile - cumT) * 128; }
    cumT += nt;
  }
  off = (e >= 0) ? e * ECAP : 0;
  return e >= 0;
}

// ---------------- fused gate+up GEMM + SwiGLU (128x128, dbuf) ----------------
// (256,2): 128 AGPR acc + ~90 VGPR ~ 220 regs/wave; 3 waves/SIMD cap=170 -> SPILLS
// (round-3 regression: WRITE_SIZE 243MB). Do not raise.
__global__ __launch_bounds__(256, 2) void gateup_kernel(
    const unsigned short* __restrict__ xb,
    const unsigned short* __restrict__ wgb,
    const unsigned short* __restrict__ wub,
    const int* __restrict__ counts,
    const int* __restrict__ rowmap,
    const float* __restrict__ roww,
    unsigned short* __restrict__ act){
  const int b = blockIdx.x;
  int e, off, ne, m0;
  if (!tile_map(counts, b >> 2, e, off, ne, m0)) return;
  const int n0 = (b & 3) * 128;

  __shared__ unsigned short sA [2][128*32];
  __shared__ unsigned short sBg[2][128*32];
  __shared__ unsigned short sBu[2][128*32];
  __shared__ int sT[128];

  const int tid  = threadIdx.x;
  const int lane = tid & 63;
  const int wid  = tid >> 6;

  if (tid < 128){
    int r = m0 + tid;
    sT[tid] = rowmap[off + ((r < ne) ? r : 0)];
  }
  __syncthreads();

  const int r_in = lane >> 2;
  const int seg  = lane & 3;
  const int rt0  = wid*32 + r_in;
  const int rt1  = rt0 + 16;
  const size_t wbase = (size_t)e * Id * Hd;

  const unsigned short* pA0 = xb + (size_t)sT[rt0]*Hd + seg*8;
  const unsigned short* pA1 = xb + (size_t)sT[rt1]*Hd + seg*8;
  const unsigned short* pG0 = wgb + wbase + (size_t)(n0+rt0)*Hd + seg*8;
  const unsigned short* pG1 = wgb + wbase + (size_t)(n0+rt1)*Hd + seg*8;
  const unsigned short* pU0 = wub + wbase + (size_t)(n0+rt0)*Hd + seg*8;
  const unsigned short* pU1 = wub + wbase + (size_t)(n0+rt1)*Hd + seg*8;
  const int dA0 = wid*1024;
  const int dA1 = wid*1024 + 512;

  floatx4 accg[4][4], accu[4][4];
  #pragma unroll
  for (int i = 0; i < 4; ++i)
    #pragma unroll
    for (int j = 0; j < 4; ++j){
      floatx4 z = {0.f,0.f,0.f,0.f};
      accg[i][j] = z; accu[i][j] = z;
    }

  const int wm = (wid & 1) * 64;
  const int wn = (wid >> 1) * 64;
  const int fm = lane & 15;
  const int fq = lane >> 4;

  load_lds16(pA0, &sA[0][dA0]);  load_lds16(pA1, &sA[0][dA1]);
  load_lds16(pG0, &sBg[0][dA0]); load_lds16(pG1, &sBg[0][dA1]);
  load_lds16(pU0, &sBu[0][dA0]); load_lds16(pU1, &sBu[0][dA1]);

  #pragma unroll 2
  for (int kit = 0; kit < 32; ++kit){
    const int cur = kit & 1;
    if (kit < 31){
      const int nk = (kit+1)*32;
      const int nb = 1 - cur;
      load_lds16(pA0 + nk, &sA[nb][dA0]);  load_lds16(pA1 + nk, &sA[nb][dA1]);
      load_lds16(pG0 + nk, &sBg[nb][dA0]); load_lds16(pG1 + nk, &sBg[nb][dA1]);
      load_lds16(pU0 + nk, &sBu[nb][dA0]); load_lds16(pU1 + nk, &sBu[nb][dA1]);
      WAIT_VM(6);
    } else {
      WAIT_VM(0);
    }
    wg_barrier();
    bf16x8 av[4], bgv[4], buv[4];
    #pragma unroll
    for (int i = 0; i < 4; ++i)
      av[i] = *(const bf16x8*)(&sA[cur][(wm + i*16 + fm)*32 + fq*8]);
    #pragma unroll
    for (int j = 0; j < 4; ++j){
      bgv[j] = *(const bf16x8*)(&sBg[cur][(wn + j*16 + fm)*32 + fq*8]);
      buv[j] = *(const bf16x8*)(&sBu[cur][(wn + j*16 + fm)*32 + fq*8]);
    }
    #pragma unroll
    for (int i = 0; i < 4; ++i)
      #pragma unroll
      for (int j = 0; j < 4; ++j){
        accg[i][j] = __builtin_amdgcn_mfma_f32_16x16x32_bf16(av[i], bgv[j], accg[i][j], 0, 0, 0);
        accu[i][j] = __builtin_amdgcn_mfma_f32_16x16x32_bf16(av[i], buv[j], accu[i][j], 0, 0, 0);
      }
    wg_barrier();
  }

  #pragma unroll
  for (int i = 0; i < 4; ++i){
    #pragma unroll
    for (int r = 0; r < 4; ++r){
      int row = wm + i*16 + fq*4 + r;
      if (m0 + row < ne){
        float w = roww[off + m0 + row];
        size_t rb = (size_t)(off + m0 + row) * Id + n0;
        #pragma unroll
        for (int j = 0; j < 4; ++j){
          float g = accg[i][j][r];
          float u = accu[i][j][r];
          float a = (g / (1.f + __expf(-g))) * u * w;
          act[rb + wn + j*16 + fm] = f2bf(a);
        }
      }
    }
  }
}

// ---------------- down GEMM + atomic scatter (dbuf) ----------------
// (256,4): 64 AGPR acc + ~60 VGPR = 124 <= 128 cap -> no spill.
__global__ __launch_bounds__(256, 4) void down_kernel(
    const unsigned short* __restrict__ act,
    const unsigned short* __restrict__ wdb,
    const int* __restrict__ counts,
    const int* __restrict__ rowmap,
    float* __restrict__ out){
  const int b = blockIdx.x;
  int e, off, ne, m0;
  if (!tile_map(counts, b >> 3, e, off, ne, m0)) return;
  const int n0 = (b & 7) * 128;

  __shared__ unsigned short sA[2][128*32];
  __shared__ unsigned short sB[2][128*32];
  __shared__ int sT[128];

  const int tid  = threadIdx.x;
  const int lane = tid & 63;
  const int wid  = tid >> 6;
  if (tid < 128){
    int r = m0 + tid;
    sT[tid] = (r < ne) ? rowmap[off + r] : 0;
  }

  const int r_in = lane >> 2, seg = lane & 3;
  const int rt0 = wid*32 + r_in;
  const int rt1 = rt0 + 16;
  const int gr0 = off + ((m0 + rt0 < ne) ? (m0 + rt0) : 0);
  const int gr1 = off + ((m0 + rt1 < ne) ? (m0 + rt1) : 0);
  const size_t wbase = (size_t)e * Hd * Id;
  const unsigned short* pA0 = act + (size_t)gr0*Id + seg*8;
  const unsigned short* pA1 = act + (size_t)gr1*Id + seg*8;
  const unsigned short* pB0 = wdb + wbase + (size_t)(n0+rt0)*Id + seg*8;
  const unsigned short* pB1 = wdb + wbase + (size_t)(n0+rt1)*Id + seg*8;
  const int dA0 = wid*1024, dA1 = wid*1024 + 512;

  floatx4 acc[4][4];
  #pragma unroll
  for (int i = 0; i < 4; ++i)
    #pragma unroll
    for (int j = 0; j < 4; ++j){ floatx4 z = {0.f,0.f,0.f,0.f}; acc[i][j] = z; }

  const int wm = (wid & 1) * 64, wn = (wid >> 1) * 64;
  const int fm = lane & 15, fq = lane >> 4;

  load_lds16(pA0, &sA[0][dA0]); load_lds16(pA1, &sA[0][dA1]);
  load_lds16(pB0, &sB[0][dA0]); load_lds16(pB1, &sB[0][dA1]);

  #pragma unroll 2
  for (int kit = 0; kit < 16; ++kit){
    const int cur = kit & 1;
    if (kit < 15){
      const int nk = (kit+1)*32;
      const int nb = 1 - cur;
      load_lds16(pA0 + nk, &sA[nb][dA0]); load_lds16(pA1 + nk, &sA[nb][dA1]);
      load_lds16(pB0 + nk, &sB[nb][dA0]); load_lds16(pB1 + nk, &sB[nb][dA1]);
      WAIT_VM(4);
    } else {
      WAIT_VM(0);
    }
    wg_barrier();
    bf16x8 av[4], bv[4];
    #pragma unroll
    for (int i = 0; i < 4; ++i) av[i] = *(const bf16x8*)(&sA[cur][(wm + i*16 + fm)*32 + fq*8]);
    #pragma unroll
    for (int j = 0; j < 4; ++j) bv[j] = *(const bf16x8*)(&sB[cur][(wn + j*16 + fm)*32 + fq*8]);
    #pragma unroll
    for (int i = 0; i < 4; ++i)
      #pragma unroll
      for (int j = 0; j < 4; ++j)
        acc[i][j] = __builtin_amdgcn_mfma_f32_16x16x32_bf16(av[i], bv[j], acc[i][j], 0, 0, 0);
    wg_barrier();
  }

  #pragma unroll
  for (int i = 0; i < 4; ++i){
    #pragma unroll
    for (int r = 0; r < 4; ++r){
      int row = wm + i*16 + fq*4 + r;
      if (m0 + row < ne){
        int t = sT[row];
        #pragma unroll
        for (int j = 0; j < 4; ++j)
          atomicAdd(&out[(size_t)t*Hd + n0 + wn + j*16 + fm], acc[i][j][r]);
      }
    }
  }
}

// =================================================================
extern "C" void kernel_launch(void* const* d_in, const int* in_sizes, int n_in,
                              void* d_out, int out_size, void* d_ws, size_t ws_size,
                              hipStream_t stream){
  (void)in_sizes; (void)n_in; (void)out_size; (void)ws_size;
  const float* x    = (const float*)d_in[0];
  const float* rw   = (const float*)d_in[1];
  const float* bias = (const float*)d_in[2];
  const float* wg   = (const float*)d_in[3];
  const float* wu   = (const float*)d_in[4];
  const float* wd   = (const float*)d_in[5];
  float* out = (float*)d_out;

  char* ws = (char*)d_ws;
  const size_t WSZ = (size_t)NE * Id * Hd * 2;
  unsigned short* wgb = (unsigned short*)(ws);
  unsigned short* wub = (unsigned short*)(ws + WSZ);
  unsigned short* wdb = (unsigned short*)(ws + 2*WSZ);
  unsigned short* xb  = (unsigned short*)(ws + 3*WSZ);
  unsigned short* act = (unsigned short*)(ws + 3*WSZ + (size_t)T_TOK*Hd*2);  // NE*ECAP*Id bf16 = 16MB
  char* misc = ws + 3*WSZ + (size_t)T_TOK*Hd*2 + (size_t)NE*ECAP*Id*2;

  const size_t LOGB = (size_t)T_TOK * NSLOT * 4;
  float* logits  = (float*)misc;
  int*   cursors = (int*)(misc + LOGB);        // doubles as counts
  char* p2 = misc + LOGB + 256;
  int*   rowmap = (int*)p2;                     p2 += (size_t)NE*ECAP*4;
  float* roww   = (float*)p2;

  prep_kernel<<<1792, 256, 0, stream>>>(wg, wu, wd, x, rw,
                                        wgb, wub, wdb, xb, logits, cursors);
  topk_kernel<<<T_TOK/8, 256, 0, stream>>>(logits, bias, x, cursors, rowmap, roww, out);
  gateup_kernel<<<MAXT*4, 256, 0, stream>>>(xb, wgb, wub, cursors, rowmap, roww, act);
  down_kernel<<<MAXT*8, 256, 0, stream>>>(act, wdb, cursors, rowmap, out);
}